// Round 1
// baseline (14388.512 us; speedup 1.0000x reference)
//
#include <hip/hip_runtime.h>
#include <hip/hip_bf16.h>
#include <math.h>

#define NV 32000
#define NE 1024
#define NH 1024
#define NB 64
#define NT 64
#define NS 128

__device__ __forceinline__ float sigmoidf_(float x){ return 1.f/(1.f+__expf(-x)); }
__device__ __forceinline__ float fast_tanh(float x){
  float a = fabsf(x);
  float e = __expf(-2.f*a);
  float t = (1.f-e)/(1.f+e);
  return x < 0.f ? -t : t;
}

// ---- init hidden double buffers from h0 [L,B,H]
__global__ __launch_bounds__(256) void k_init(const float* __restrict__ h0,
    float* __restrict__ h0b, float* __restrict__ h1b){
  int b = blockIdx.x;
  const float4* s0 = (const float4*)(h0 + (size_t)b*NH);
  const float4* s1 = (const float4*)(h0 + (size_t)NB*NH + (size_t)b*NH);
  ((float4*)(h0b + (size_t)b*NH))[threadIdx.x] = s0[threadIdx.x];
  ((float4*)(h1b + (size_t)b*NH))[threadIdx.x] = s1[threadIdx.x];
}

// ---- generic fp32 GEMM  C[m][n] = sum_k A[m][k]*W[n][k] + bias[n]
// BM=BN=128, BK=8, 256 threads, 8x8 per thread. M%128==0, N%128==0, K%8==0.
__global__ __launch_bounds__(256) void k_gemm_bias(
    const float* __restrict__ A, const float* __restrict__ W,
    const float* __restrict__ bias, float* __restrict__ C,
    int M, int N, int K){
  __shared__ float As[8][128];
  __shared__ float Ws[8][128];
  int m0 = blockIdx.y * 128, n0 = blockIdx.x * 128;
  int tid = threadIdx.x;
  int mg = tid >> 4, ng = tid & 15;
  float acc[8][8];
  #pragma unroll
  for (int i=0;i<8;++i)
    #pragma unroll
    for (int j=0;j<8;++j) acc[i][j]=0.f;
  int lm = tid >> 1;
  int lk = (tid & 1) * 4;
  for (int k0 = 0; k0 < K; k0 += 8){
    float4 av = *(const float4*)(A + (size_t)(m0+lm)*K + k0 + lk);
    float4 wv_ = *(const float4*)(W + (size_t)(n0+lm)*K + k0 + lk);
    As[lk+0][lm]=av.x; As[lk+1][lm]=av.y; As[lk+2][lm]=av.z; As[lk+3][lm]=av.w;
    Ws[lk+0][lm]=wv_.x; Ws[lk+1][lm]=wv_.y; Ws[lk+2][lm]=wv_.z; Ws[lk+3][lm]=wv_.w;
    __syncthreads();
    #pragma unroll
    for (int k=0;k<8;++k){
      float a[8], bb[8];
      *(float4*)&a[0] = *(const float4*)&As[k][mg*8];
      *(float4*)&a[4] = *(const float4*)&As[k][mg*8+4];
      *(float4*)&bb[0] = *(const float4*)&Ws[k][ng*8];
      *(float4*)&bb[4] = *(const float4*)&Ws[k][ng*8+4];
      #pragma unroll
      for (int i=0;i<8;++i)
        #pragma unroll
        for (int j=0;j<8;++j) acc[i][j] += a[i]*bb[j];
    }
    __syncthreads();
  }
  #pragma unroll
  for (int i=0;i<8;++i){
    int m = m0 + mg*8 + i;
    #pragma unroll
    for (int j4=0;j4<2;++j4){
      int n = n0 + ng*8 + j4*4;
      float4 o;
      o.x = acc[i][j4*4+0] + bias[n+0];
      o.y = acc[i][j4*4+1] + bias[n+1];
      o.z = acc[i][j4*4+2] + bias[n+2];
      o.w = acc[i][j4*4+3] + bias[n+3];
      *(float4*)(C + (size_t)m*N + n) = o;
    }
  }
}

// ---- K-split partial GEMM with two (A,W) phases (for GRU gi/gh and q).
// M fixed = 64. Chunk kc<nc1 -> phase1 (A1,W1), else phase2 (A2,W2).
// part[kc][64][N] = sum_{k in chunk kc} A[m][k]*W[n][k]   (no bias)
template<int BN>
__global__ __launch_bounds__(256) void k_gemm2_part(
    const float* __restrict__ A1, const float* __restrict__ W1, int sA1, int sW1, int nc1,
    const float* __restrict__ A2, const float* __restrict__ W2, int sA2, int sW2,
    int CK, int N, float* __restrict__ part){
  constexpr int BK = 16;
  constexpr int NJ = BN/16;   // 4 for BN=64, 1 for BN=16
  __shared__ float As[BK][64];
  __shared__ float Ws[BK][BN];
  int kc = blockIdx.y;
  const float* A; const float* W; int sA, sW, kbase;
  if (kc < nc1){ A=A1; W=W1; sA=sA1; sW=sW1; kbase = kc*CK; }
  else        { A=A2; W=W2; sA=sA2; sW=sW2; kbase = (kc-nc1)*CK; }
  int n0 = blockIdx.x * BN;
  int tid = threadIdx.x;
  int mg = tid >> 4, ng = tid & 15;
  float acc[4][NJ];
  #pragma unroll
  for (int i=0;i<4;++i)
    #pragma unroll
    for (int j=0;j<NJ;++j) acc[i][j]=0.f;
  int lm = tid >> 2, lk = (tid & 3)*4;
  for (int k0=0;k0<CK;k0+=BK){
    float4 av = *(const float4*)(A + (size_t)lm*sA + kbase + k0 + lk);
    As[lk+0][lm]=av.x; As[lk+1][lm]=av.y; As[lk+2][lm]=av.z; As[lk+3][lm]=av.w;
    if (BN==64){
      float4 wv_ = *(const float4*)(W + (size_t)(n0+lm)*sW + kbase + k0 + lk);
      Ws[lk+0][lm]=wv_.x; Ws[lk+1][lm]=wv_.y; Ws[lk+2][lm]=wv_.z; Ws[lk+3][lm]=wv_.w;
    } else {
      int ln = tid >> 4, lkk = tid & 15;
      Ws[lkk][ln] = W[(size_t)(n0+ln)*sW + kbase + k0 + lkk];
    }
    __syncthreads();
    #pragma unroll
    for (int k=0;k<BK;++k){
      float a[4];
      *(float4*)&a[0] = *(const float4*)&As[k][mg*4];
      if (NJ==4){
        float bb[4];
        *(float4*)&bb[0] = *(const float4*)&Ws[k][ng*4];
        #pragma unroll
        for (int i=0;i<4;++i)
          #pragma unroll
          for (int j=0;j<4;++j) acc[i][j] += a[i]*bb[j];
      } else {
        float bb = Ws[k][ng];
        #pragma unroll
        for (int i=0;i<4;++i) acc[i][0] += a[i]*bb;
      }
    }
    __syncthreads();
  }
  #pragma unroll
  for (int i=0;i<4;++i){
    int m = mg*4 + i;
    if (NJ==4){
      float4 o; o.x=acc[i][0]; o.y=acc[i][1]; o.z=acc[i][2]; o.w=acc[i][3];
      *(float4*)(part + ((size_t)kc*64 + m)*N + n0 + ng*4) = o;
    } else {
      part[((size_t)kc*64 + m)*N + n0 + ng] = acc[i][0];
    }
  }
}

// ---- attention step: q = sum(qpart)+bq; scores=tanh(q+kproj)@wv+bv; softmax;
//      ctx = attn@encY -> A0[:,0:1024]; x gather -> A0[:,1024:2048]
__global__ __launch_bounds__(256) void k_attn(
    const float* __restrict__ qpart, const float* __restrict__ bq,
    const float* __restrict__ kproj, const float* __restrict__ encY,
    const float* __restrict__ wv, const float* __restrict__ bv,
    const int* __restrict__ X, const float* __restrict__ table, int t,
    float* __restrict__ A0){
  int b = blockIdx.x, tid = threadIdx.x;
  __shared__ float qs[NH];
  __shared__ float wvs[NH];
  __shared__ float sc[NS];
  for (int i = tid; i < NH; i += 256){
    qs[i] = bq[i] + qpart[(size_t)(0*NB+b)*NH+i] + qpart[(size_t)(1*NB+b)*NH+i]
                  + qpart[(size_t)(2*NB+b)*NH+i] + qpart[(size_t)(3*NB+b)*NH+i];
    wvs[i] = wv[i];
  }
  __syncthreads();
  int wave = tid >> 6, lane = tid & 63;
  for (int s = wave; s < NS; s += 4){
    const float* kp = kproj + ((size_t)b*NS + s)*NH;
    float acc = 0.f;
    #pragma unroll
    for (int j=0;j<4;++j){
      int h = j*256 + lane*4;
      float4 kv = *(const float4*)(kp + h);
      float4 qv = *(const float4*)(qs + h);
      float4 wk = *(const float4*)(wvs + h);
      acc += fast_tanh(qv.x+kv.x)*wk.x;
      acc += fast_tanh(qv.y+kv.y)*wk.y;
      acc += fast_tanh(qv.z+kv.z)*wk.z;
      acc += fast_tanh(qv.w+kv.w)*wk.w;
    }
    #pragma unroll
    for (int off=32; off>0; off>>=1) acc += __shfl_down(acc, off);
    if (lane==0) sc[s] = acc + bv[0];
  }
  __syncthreads();
  if (tid < 64){
    float v0 = sc[tid], v1 = sc[tid+64];
    float mx = fmaxf(v0, v1);
    #pragma unroll
    for (int off=32; off>0; off>>=1) mx = fmaxf(mx, __shfl_xor(mx, off));
    float e0 = __expf(v0-mx), e1 = __expf(v1-mx);
    float sm = e0+e1;
    #pragma unroll
    for (int off=32; off>0; off>>=1) sm += __shfl_xor(sm, off);
    float inv = 1.f/sm;
    sc[tid] = e0*inv; sc[tid+64] = e1*inv;
  }
  __syncthreads();
  float4 acc = {0.f,0.f,0.f,0.f};
  const float* ey = encY + (size_t)b*NS*NH;
  #pragma unroll 4
  for (int s=0;s<NS;++s){
    float w = sc[s];
    float4 v = *(const float4*)(ey + (size_t)s*NH + tid*4);
    acc.x += w*v.x; acc.y += w*v.y; acc.z += w*v.z; acc.w += w*v.w;
  }
  *(float4*)(A0 + (size_t)b*2048 + tid*4) = acc;
  int tok = X[b*NT + t];
  float4 xv = *(const float4*)(table + (size_t)tok*NE + tid*4);
  *(float4*)(A0 + (size_t)b*2048 + NE + tid*4) = xv;
}

// ---- GRU cell: sum partial chunks, apply gates, write new h
__global__ __launch_bounds__(256) void k_gru_cell(
    const float* __restrict__ part, int ncI, int ncH,
    const float* __restrict__ bih, const float* __restrict__ bhh,
    const float* __restrict__ hprev,
    float* __restrict__ outA, float* __restrict__ outB,
    float* __restrict__ ys, int t){
  int b = blockIdx.x;
  #pragma unroll
  for (int jj=0;jj<4;++jj){
    int j = threadIdx.x + jj*256;
    float ir=0.f,iz=0.f,inn=0.f,hr=0.f,hz=0.f,hn=0.f;
    for (int kc=0;kc<ncI;++kc){
      const float* p = part + ((size_t)kc*NB + b)*3072;
      ir += p[j]; iz += p[NH+j]; inn += p[2*NH+j];
    }
    for (int kc=ncI;kc<ncI+ncH;++kc){
      const float* p = part + ((size_t)kc*NB + b)*3072;
      hr += p[j]; hz += p[NH+j]; hn += p[2*NH+j];
    }
    float r = sigmoidf_(ir+hr+bih[j]+bhh[j]);
    float z = sigmoidf_(iz+hz+bih[NH+j]+bhh[NH+j]);
    float n = tanhf(inn + bih[2*NH+j] + r*(hn + bhh[2*NH+j]));
    float hp = hprev[(size_t)b*NH + j];
    float h = (1.f - z)*n + z*hp;
    outA[(size_t)b*NH + j] = h;
    if (outB) outB[(size_t)b*NH + j] = h;
    if (ys) ys[((size_t)b*NT + t)*NH + j] = h;
  }
}

// ---- in-place log-softmax over rows of length NV
__global__ __launch_bounds__(256) void k_logsoftmax(float* __restrict__ out){
  int r = blockIdx.x;
  float4* row = (float4*)(out + (size_t)r*NV);
  int tid = threadIdx.x;
  int lane = tid & 63, wave = tid >> 6;
  __shared__ float red0[4], red1[4];
  const int N4 = NV/4; // 8000
  float mx = -INFINITY;
  for (int i = tid; i < N4; i += 256){
    float4 v = row[i];
    mx = fmaxf(mx, fmaxf(fmaxf(v.x,v.y), fmaxf(v.z,v.w)));
  }
  #pragma unroll
  for (int off=32; off>0; off>>=1) mx = fmaxf(mx, __shfl_xor(mx, off));
  if (lane==0) red0[wave]=mx;
  __syncthreads();
  mx = fmaxf(fmaxf(red0[0],red0[1]), fmaxf(red0[2],red0[3]));
  float sm = 0.f;
  for (int i = tid; i < N4; i += 256){
    float4 v = row[i];
    sm += __expf(v.x-mx)+__expf(v.y-mx)+__expf(v.z-mx)+__expf(v.w-mx);
  }
  #pragma unroll
  for (int off=32; off>0; off>>=1) sm += __shfl_xor(sm, off);
  if (lane==0) red1[wave]=sm;
  __syncthreads();
  sm = red1[0]+red1[1]+red1[2]+red1[3];
  float lse = mx + logf(sm);
  for (int i = tid; i < N4; i += 256){
    float4 v = row[i];
    v.x -= lse; v.y -= lse; v.z -= lse; v.w -= lse;
    row[i] = v;
  }
}

extern "C" void kernel_launch(void* const* d_in, const int* in_sizes, int n_in,
                              void* d_out, int out_size, void* d_ws, size_t ws_size,
                              hipStream_t stream) {
  const int*   X     = (const int*)  d_in[0];
  const float* encY  = (const float*)d_in[1];
  const float* h0    = (const float*)d_in[2];
  const float* table = (const float*)d_in[3];
  const float* Wq    = (const float*)d_in[4];
  const float* bq    = (const float*)d_in[5];
  const float* Wk    = (const float*)d_in[6];
  const float* bk    = (const float*)d_in[7];
  const float* wv    = (const float*)d_in[8];
  const float* bv    = (const float*)d_in[9];
  const float* Wih0  = (const float*)d_in[10];
  const float* Whh0  = (const float*)d_in[11];
  const float* bih0  = (const float*)d_in[12];
  const float* bhh0  = (const float*)d_in[13];
  const float* Wih1  = (const float*)d_in[14];
  const float* Whh1  = (const float*)d_in[15];
  const float* bih1  = (const float*)d_in[16];
  const float* bhh1  = (const float*)d_in[17];
  const float* Wout  = (const float*)d_in[18];
  const float* bout  = (const float*)d_in[19];
  float* out = (float*)d_out;
  float* ws  = (float*)d_ws;

  // ws layout (floats)
  float* kproj = ws;                        // 64*128*1024      = 8388608
  float* ys    = kproj + (size_t)8388608;   // 64*64*1024       = 4194304
  float* A0    = ys + (size_t)4194304;      // 64*2048          = 131072
  float* h0b   = A0 + 131072;               // 2*64*1024        = 131072
  float* h1b   = h0b + 131072;              // 2*64*1024        = 131072
  float* h0new = h1b + 131072;              // 64*1024          = 65536
  float* qpart = h0new + 65536;             // 4*64*1024        = 262144
  float* g0p   = qpart + 262144;            // 6*64*3072        = 1179648
  float* g1p   = g0p + 1179648;             // 4*64*3072        = 786432

  k_init<<<dim3(NB), dim3(256), 0, stream>>>(h0, h0b, h1b);
  // kproj = encY @ Wk^T + bk : M=8192, N=1024, K=1024
  k_gemm_bias<<<dim3(1024/128, 8192/128), dim3(256), 0, stream>>>(
      encY, Wk, bk, kproj, 8192, 1024, 1024);

  for (int t = 0; t < NT; ++t){
    int cur = t & 1, nxt = cur ^ 1;
    float* h0cur = h0b + (size_t)cur*65536;
    float* h0nxt = h0b + (size_t)nxt*65536;
    float* h1cur = h1b + (size_t)cur*65536;
    float* h1nxt = h1b + (size_t)nxt*65536;

    // q partials: h1cur @ Wq^T, K=1024 in 4 chunks of 256
    k_gemm2_part<16><<<dim3(1024/16, 4), dim3(256), 0, stream>>>(
        h1cur, Wq, 1024, 1024, 4, h1cur, Wq, 1024, 1024, 256, 1024, qpart);
    // attention + x gather -> A0
    k_attn<<<dim3(NB), dim3(256), 0, stream>>>(
        qpart, bq, kproj, encY, wv, bv, X, table, t, A0);
    // GRU0 gates partials: phase1 A0@Wih0 (K=2048, 4 chunks), phase2 h0cur@Whh0 (K=1024, 2 chunks)
    k_gemm2_part<64><<<dim3(3072/64, 6), dim3(256), 0, stream>>>(
        A0, Wih0, 2048, 2048, 4, h0cur, Whh0, 1024, 1024, 512, 3072, g0p);
    k_gru_cell<<<dim3(NB), dim3(256), 0, stream>>>(
        g0p, 4, 2, bih0, bhh0, h0cur, h0new, h0nxt, nullptr, 0);
    // GRU1 gates partials: phase1 h0new@Wih1 (2 chunks), phase2 h1cur@Whh1 (2 chunks)
    k_gemm2_part<64><<<dim3(3072/64, 4), dim3(256), 0, stream>>>(
        h0new, Wih1, 1024, 1024, 2, h1cur, Whh1, 1024, 1024, 512, 3072, g1p);
    k_gru_cell<<<dim3(NB), dim3(256), 0, stream>>>(
        g1p, 2, 2, bih1, bhh1, h1cur, h1nxt, nullptr, ys, t);
  }

  // logits -> d_out : ys[4096,1024] @ Wout^T[1024,32000] + bout, then log-softmax in place
  k_gemm_bias<<<dim3(NV/128, 4096/128), dim3(256), 0, stream>>>(
      ys, Wout, bout, out, 4096, NV, 1024);
  k_logsoftmax<<<dim3(4096), dim3(256), 0, stream>>>(out);
}

// Round 2
// 7281.436 us; speedup vs baseline: 1.9761x; 1.9761x over previous
//
#include <hip/hip_runtime.h>
#include <hip/hip_bf16.h>
#include <math.h>

#define NV 32000
#define NE 1024
#define NH 1024
#define NB 64
#define NT 64
#define NS 128

typedef short bf16x8 __attribute__((ext_vector_type(8)));
typedef float f32x4 __attribute__((ext_vector_type(4)));

typedef __attribute__((address_space(1))) const void* gvoidp;
typedef __attribute__((address_space(3))) void* svoidp;
__device__ __forceinline__ void gload16(const void* g, void* s){
  __builtin_amdgcn_global_load_lds((gvoidp)g, (svoidp)s, 16, 0, 0);
}

__device__ __forceinline__ unsigned short f2bf(float f){
  unsigned u = __float_as_uint(f);
  u += 0x7fff + ((u>>16)&1);
  return (unsigned short)(u>>16);
}
__device__ __forceinline__ float bf2f(unsigned short h){
  return __uint_as_float(((unsigned)h)<<16);
}
__device__ __forceinline__ float sigmoidf_(float x){ return 1.f/(1.f+__expf(-x)); }
__device__ __forceinline__ float fast_tanh(float x){
  float a = fabsf(x);
  float e = __expf(-2.f*a);
  float t = (1.f-e)/(1.f+e);
  return x < 0.f ? -t : t;
}

// ---- f32 -> bf16 bulk convert (n4 = count of float4 groups)
__global__ __launch_bounds__(256) void k_f2bf(const float* __restrict__ src,
    unsigned short* __restrict__ dst, int n4){
  int i = blockIdx.x*256 + threadIdx.x;
  int stride = gridDim.x*256;
  for (; i < n4; i += stride){
    float4 v = ((const float4*)src)[i];
    ushort4 o;
    o.x = f2bf(v.x); o.y = f2bf(v.y); o.z = f2bf(v.z); o.w = f2bf(v.w);
    ((ushort4*)dst)[i] = o;
  }
}

// ---- init hidden buffers (fp32 + bf16) from h0 [L,B,H]
__global__ __launch_bounds__(256) void k_init(const float* __restrict__ h0,
    float* __restrict__ h0f, float* __restrict__ h1f,
    unsigned short* __restrict__ h0h, unsigned short* __restrict__ h1h){
  int b = blockIdx.x, tid = threadIdx.x;
  float4 v0 = ((const float4*)(h0 + (size_t)b*NH))[tid];
  float4 v1 = ((const float4*)(h0 + (size_t)(NB + b)*NH))[tid];
  ((float4*)(h0f + (size_t)b*NH))[tid] = v0;
  ((float4*)(h1f + (size_t)b*NH))[tid] = v1;
  ushort4 a, c;
  a.x=f2bf(v0.x); a.y=f2bf(v0.y); a.z=f2bf(v0.z); a.w=f2bf(v0.w);
  c.x=f2bf(v1.x); c.y=f2bf(v1.y); c.z=f2bf(v1.z); c.w=f2bf(v1.w);
  ((ushort4*)(h0h + (size_t)b*NH))[tid] = a;
  ((ushort4*)(h1h + (size_t)b*NH))[tid] = c;
}

// ---- bf16 MFMA GEMM, m97 structure: 128x128 tile, BK=64, 4 waves (2x2), 4x4 frags
// C[m][n] = sum_k A[m][k] * W[n][k] + bias[n]. M%128==0, N%128==0, K%64==0.
// OUTBF: 1 -> store bf16, 0 -> store f32
template<int OUTBF>
__global__ __launch_bounds__(256) void k_mfma_gemm(
    const unsigned short* __restrict__ A, const unsigned short* __restrict__ W,
    const float* __restrict__ bias, void* __restrict__ C,
    int M, int N, int K){
  __shared__ unsigned short As[128*64];
  __shared__ unsigned short Bs[128*64];
  int gx = gridDim.x;
  int total = gx * gridDim.y;
  int lin = blockIdx.y * gx + blockIdx.x;
  int swz = (lin & 7) * (total >> 3) + (lin >> 3);   // grid %8==0 guaranteed by launch
  int bm = swz / gx, bn = swz - bm*gx;
  int m0 = bm * 128, n0 = bn * 128;
  int tid = threadIdx.x;
  int w = tid >> 6, l = tid & 63;
  int wr = w >> 1, wc = w & 1;
  int fr = l & 15, fq = l >> 4;
  f32x4 acc[4][4] = {};
  int sr = tid >> 3;              // staging row sub-index 0..31
  int sc = (tid & 7) * 16;        // staging byte col 0..112

  for (int k0 = 0; k0 < K; k0 += 64){
    #pragma unroll
    for (int i = 0; i < 4; ++i){
      int r = i*32 + sr;
      int cs = sc ^ ((r & 7) << 4);
      const char* ga = (const char*)(A + (size_t)(m0 + r)*K + k0) + cs;
      const char* gb = (const char*)(W + (size_t)(n0 + r)*K + k0) + cs;
      gload16(ga, (char*)As + i*4096 + w*1024);
      gload16(gb, (char*)Bs + i*4096 + w*1024);
    }
    __syncthreads();
    #pragma unroll
    for (int ks = 0; ks < 2; ++ks){
      bf16x8 af[4], bfg[4];
      int kb = ks*64 + fq*16;
      #pragma unroll
      for (int mi = 0; mi < 4; ++mi){
        int r = wr*64 + mi*16 + fr;
        af[mi] = *(const bf16x8*)((const char*)As + r*128 + (kb ^ ((r&7)<<4)));
      }
      #pragma unroll
      for (int ni = 0; ni < 4; ++ni){
        int r = wc*64 + ni*16 + fr;
        bfg[ni] = *(const bf16x8*)((const char*)Bs + r*128 + (kb ^ ((r&7)<<4)));
      }
      #pragma unroll
      for (int mi = 0; mi < 4; ++mi)
        #pragma unroll
        for (int ni = 0; ni < 4; ++ni)
          acc[mi][ni] = __builtin_amdgcn_mfma_f32_16x16x32_bf16(af[mi], bfg[ni], acc[mi][ni], 0, 0, 0);
    }
    __syncthreads();
  }
  #pragma unroll
  for (int mi = 0; mi < 4; ++mi){
    #pragma unroll
    for (int ni = 0; ni < 4; ++ni){
      int n = n0 + wc*64 + ni*16 + fr;
      float bv_ = bias[n];
      #pragma unroll
      for (int v = 0; v < 4; ++v){
        int m = m0 + wr*64 + mi*16 + fq*4 + v;
        float val = acc[mi][ni][v] + bv_;
        if (OUTBF) ((unsigned short*)C)[(size_t)m*N + n] = f2bf(val);
        else       ((float*)C)[(size_t)m*N + n] = val;
      }
    }
  }
}

// ---- M=64 K-split MFMA partial GEMM with two (A,W) phases.
// part[kc][64][N] = sum_{k in chunk} A[m][k]*W[n][k]  (fp32, no bias)
__global__ __launch_bounds__(256) void k_mfma_part(
    const unsigned short* __restrict__ A1, const unsigned short* __restrict__ W1,
    int sA1, int sW1, int nc1,
    const unsigned short* __restrict__ A2, const unsigned short* __restrict__ W2,
    int sA2, int sW2,
    int CK, int N, float* __restrict__ part){
  __shared__ unsigned short As[64*64];
  __shared__ unsigned short Bs[64*64];
  int kc = blockIdx.y;
  const unsigned short* A; const unsigned short* W; int sA, sW, kb0;
  if (kc < nc1){ A=A1; W=W1; sA=sA1; sW=sW1; kb0 = kc*CK; }
  else        { A=A2; W=W2; sA=sA2; sW=sW2; kb0 = (kc-nc1)*CK; }
  int n0 = blockIdx.x * 64;
  int tid = threadIdx.x, w = tid>>6, l = tid&63;
  int fr = l & 15, fq = l >> 4;
  f32x4 acc[4] = {};
  int sr = tid >> 3, sc = (tid & 7) * 16;
  for (int k0 = 0; k0 < CK; k0 += 64){
    #pragma unroll
    for (int i = 0; i < 2; ++i){
      int r = i*32 + sr;
      int cs = sc ^ ((r & 7) << 4);
      gload16((const char*)(A + (size_t)r*sA + kb0 + k0) + cs, (char*)As + i*4096 + w*1024);
      gload16((const char*)(W + (size_t)(n0 + r)*sW + kb0 + k0) + cs, (char*)Bs + i*4096 + w*1024);
    }
    __syncthreads();
    #pragma unroll
    for (int ks = 0; ks < 2; ++ks){
      int kb = ks*64 + fq*16;
      int rb = w*16 + fr;
      bf16x8 bfrag = *(const bf16x8*)((const char*)Bs + rb*128 + (kb ^ ((rb&7)<<4)));
      #pragma unroll
      for (int mi = 0; mi < 4; ++mi){
        int ra = mi*16 + fr;
        bf16x8 afrag = *(const bf16x8*)((const char*)As + ra*128 + (kb ^ ((ra&7)<<4)));
        acc[mi] = __builtin_amdgcn_mfma_f32_16x16x32_bf16(afrag, bfrag, acc[mi], 0, 0, 0);
      }
    }
    __syncthreads();
  }
  #pragma unroll
  for (int mi = 0; mi < 4; ++mi){
    int n = n0 + w*16 + fr;
    #pragma unroll
    for (int v = 0; v < 4; ++v){
      int m = mi*16 + fq*4 + v;
      part[((size_t)kc*64 + m)*N + n] = acc[mi][v];
    }
  }
}

// ---- attention step (bf16 kproj/encY), writes A0 = [ctx|emb] in bf16
__global__ __launch_bounds__(256) void k_attn(
    const float* __restrict__ qpart, const float* __restrict__ bq,
    const unsigned short* __restrict__ kproj, const unsigned short* __restrict__ encY,
    const float* __restrict__ wv, const float* __restrict__ bv,
    const int* __restrict__ X, const float* __restrict__ table, int t,
    unsigned short* __restrict__ A0){
  int b = blockIdx.x, tid = threadIdx.x;
  __shared__ float qs[NH];
  __shared__ float wvs[NH];
  __shared__ float sc[NS];
  for (int i = tid; i < NH; i += 256){
    qs[i] = bq[i] + qpart[(size_t)(0*NB+b)*NH+i] + qpart[(size_t)(1*NB+b)*NH+i]
                  + qpart[(size_t)(2*NB+b)*NH+i] + qpart[(size_t)(3*NB+b)*NH+i];
    wvs[i] = wv[i];
  }
  __syncthreads();
  int wave = tid >> 6, lane = tid & 63;
  for (int s = wave; s < NS; s += 4){
    const unsigned short* kp = kproj + ((size_t)b*NS + s)*NH;
    float acc = 0.f;
    #pragma unroll
    for (int j = 0; j < 2; ++j){
      int h = j*512 + lane*8;
      bf16x8 kv = *(const bf16x8*)(kp + h);
      #pragma unroll
      for (int e = 0; e < 8; ++e){
        float kf = bf2f((unsigned short)kv[e]);
        acc += fast_tanh(qs[h+e] + kf) * wvs[h+e];
      }
    }
    #pragma unroll
    for (int off = 32; off > 0; off >>= 1) acc += __shfl_down(acc, off);
    if (lane == 0) sc[s] = acc + bv[0];
  }
  __syncthreads();
  if (tid < 64){
    float v0 = sc[tid], v1 = sc[tid+64];
    float mx = fmaxf(v0, v1);
    #pragma unroll
    for (int off = 32; off > 0; off >>= 1) mx = fmaxf(mx, __shfl_xor(mx, off));
    float e0 = __expf(v0-mx), e1 = __expf(v1-mx);
    float sm = e0 + e1;
    #pragma unroll
    for (int off = 32; off > 0; off >>= 1) sm += __shfl_xor(sm, off);
    float inv = 1.f/sm;
    sc[tid] = e0*inv; sc[tid+64] = e1*inv;
  }
  __syncthreads();
  float c0=0.f, c1=0.f, c2=0.f, c3=0.f;
  const unsigned short* ey = encY + (size_t)b*NS*NH + tid*4;
  #pragma unroll 4
  for (int s = 0; s < NS; ++s){
    float wgt = sc[s];
    ushort4 v = *(const ushort4*)(ey + (size_t)s*NH);
    c0 += wgt*bf2f(v.x); c1 += wgt*bf2f(v.y); c2 += wgt*bf2f(v.z); c3 += wgt*bf2f(v.w);
  }
  ushort4 o;
  o.x=f2bf(c0); o.y=f2bf(c1); o.z=f2bf(c2); o.w=f2bf(c3);
  *(ushort4*)(A0 + (size_t)b*2048 + tid*4) = o;
  int tok = X[b*NT + t];
  float4 xv = ((const float4*)(table + (size_t)tok*NE))[tid];
  ushort4 o2;
  o2.x=f2bf(xv.x); o2.y=f2bf(xv.y); o2.z=f2bf(xv.z); o2.w=f2bf(xv.w);
  *(ushort4*)(A0 + (size_t)b*2048 + NE + tid*4) = o2;
}

// ---- GRU cell: sum partial chunks, gates, write h (fp32 + bf16) and ys (bf16)
__global__ __launch_bounds__(256) void k_gru_cell(
    const float* __restrict__ part, int ncI, int ncH,
    const float* __restrict__ bih, const float* __restrict__ bhh,
    const float* __restrict__ hprevf,
    float* __restrict__ outf, unsigned short* __restrict__ outh,
    unsigned short* __restrict__ ysb, int t){
  int b = blockIdx.x;
  #pragma unroll
  for (int jj = 0; jj < 4; ++jj){
    int j = threadIdx.x + jj*256;
    float ir=0.f, iz=0.f, inn=0.f, hr=0.f, hz=0.f, hn=0.f;
    for (int kc = 0; kc < ncI; ++kc){
      const float* p = part + ((size_t)kc*NB + b)*3072;
      ir += p[j]; iz += p[NH+j]; inn += p[2*NH+j];
    }
    for (int kc = ncI; kc < ncI+ncH; ++kc){
      const float* p = part + ((size_t)kc*NB + b)*3072;
      hr += p[j]; hz += p[NH+j]; hn += p[2*NH+j];
    }
    float r = sigmoidf_(ir + hr + bih[j] + bhh[j]);
    float z = sigmoidf_(iz + hz + bih[NH+j] + bhh[NH+j]);
    float n = tanhf(inn + bih[2*NH+j] + r*(hn + bhh[2*NH+j]));
    float hp = hprevf[(size_t)b*NH + j];
    float h = (1.f - z)*n + z*hp;
    outf[(size_t)b*NH + j] = h;
    outh[(size_t)b*NH + j] = f2bf(h);
    if (ysb) ysb[((size_t)b*NT + t)*NH + j] = f2bf(h);
  }
}

// ---- in-place log-softmax, row cached in LDS (125 KB), 1024 threads
__global__ __launch_bounds__(1024) void k_logsoftmax(float* __restrict__ out){
  __shared__ float rowbuf[NV];
  __shared__ float red[16];
  int r = blockIdx.x;
  float4* row = (float4*)(out + (size_t)r*NV);
  int tid = threadIdx.x;
  int lane = tid & 63, wave = tid >> 6;
  const int N4 = NV/4; // 8000
  float mx = -INFINITY;
  for (int i = tid; i < N4; i += 1024){
    float4 v = row[i];
    ((float4*)rowbuf)[i] = v;
    mx = fmaxf(mx, fmaxf(fmaxf(v.x,v.y), fmaxf(v.z,v.w)));
  }
  #pragma unroll
  for (int off = 32; off > 0; off >>= 1) mx = fmaxf(mx, __shfl_xor(mx, off));
  if (lane == 0) red[wave] = mx;
  __syncthreads();
  if (tid < 64){
    float m2 = (lane < 16) ? red[lane] : -INFINITY;
    #pragma unroll
    for (int off = 8; off > 0; off >>= 1) m2 = fmaxf(m2, __shfl_xor(m2, off));
    if (lane == 0) red[0] = m2;
  }
  __syncthreads();
  mx = red[0];
  float sm = 0.f;
  for (int i = tid; i < N4; i += 1024){
    float4 v = ((float4*)rowbuf)[i];
    sm += __expf(v.x-mx) + __expf(v.y-mx) + __expf(v.z-mx) + __expf(v.w-mx);
  }
  #pragma unroll
  for (int off = 32; off > 0; off >>= 1) sm += __shfl_xor(sm, off);
  __syncthreads();
  if (lane == 0) red[wave] = sm;
  __syncthreads();
  if (tid < 64){
    float s2 = (lane < 16) ? red[lane] : 0.f;
    #pragma unroll
    for (int off = 8; off > 0; off >>= 1) s2 += __shfl_xor(s2, off);
    if (lane == 0) red[0] = s2;
  }
  __syncthreads();
  float lse = mx + logf(red[0]);
  for (int i = tid; i < N4; i += 1024){
    float4 v = ((float4*)rowbuf)[i];
    v.x -= lse; v.y -= lse; v.z -= lse; v.w -= lse;
    row[i] = v;
  }
}

extern "C" void kernel_launch(void* const* d_in, const int* in_sizes, int n_in,
                              void* d_out, int out_size, void* d_ws, size_t ws_size,
                              hipStream_t stream) {
  const int*   X     = (const int*)  d_in[0];
  const float* encY  = (const float*)d_in[1];
  const float* h0    = (const float*)d_in[2];
  const float* table = (const float*)d_in[3];
  const float* Wq    = (const float*)d_in[4];
  const float* bq    = (const float*)d_in[5];
  const float* Wk    = (const float*)d_in[6];
  const float* bk    = (const float*)d_in[7];
  const float* wv    = (const float*)d_in[8];
  const float* bv    = (const float*)d_in[9];
  const float* Wih0  = (const float*)d_in[10];
  const float* Whh0  = (const float*)d_in[11];
  const float* bih0  = (const float*)d_in[12];
  const float* bhh0  = (const float*)d_in[13];
  const float* Wih1  = (const float*)d_in[14];
  const float* Whh1  = (const float*)d_in[15];
  const float* bih1  = (const float*)d_in[16];
  const float* bhh1  = (const float*)d_in[17];
  const float* Wout  = (const float*)d_in[18];
  const float* bout  = (const float*)d_in[19];
  float* out = (float*)d_out;
  char* ws = (char*)d_ws;

  // ws layout (bytes)
  unsigned short* encY_bf  = (unsigned short*)(ws);                 size_t off = 16777216;
  unsigned short* kproj_bf = (unsigned short*)(ws + off);           off += 16777216;
  unsigned short* Wq_bf    = (unsigned short*)(ws + off);           off += 2097152;
  unsigned short* Wk_bf    = (unsigned short*)(ws + off);           off += 2097152;
  unsigned short* Wih0_bf  = (unsigned short*)(ws + off);           off += 12582912;
  unsigned short* Whh0_bf  = (unsigned short*)(ws + off);           off += 6291456;
  unsigned short* Wih1_bf  = (unsigned short*)(ws + off);           off += 6291456;
  unsigned short* Whh1_bf  = (unsigned short*)(ws + off);           off += 6291456;
  unsigned short* Wout_bf  = (unsigned short*)(ws + off);           off += 65536000;
  unsigned short* ys_bf    = (unsigned short*)(ws + off);           off += 8388608;
  unsigned short* A0bf     = (unsigned short*)(ws + off);           off += 262144;
  float* h0f   = (float*)(ws + off);                                off += 524288;  // [2][64][1024]
  float* h1f   = (float*)(ws + off);                                off += 524288;
  unsigned short* h0h = (unsigned short*)(ws + off);                off += 262144;
  unsigned short* h1h = (unsigned short*)(ws + off);                off += 262144;
  float* qpart = (float*)(ws + off);                                off += 1048576; // [4][64][1024]
  float* g0p   = (float*)(ws + off);                                off += 4718592; // [6][64][3072]
  float* g1p   = (float*)(ws + off);                                off += 3145728; // [4][64][3072]

  // ---- one-time conversions (per launch)
  struct CV { const float* s; unsigned short* d; int n4; };
  CV cvs[8] = {
    { encY, encY_bf, 2097152 },
    { Wq,   Wq_bf,   262144 },
    { Wk,   Wk_bf,   262144 },
    { Wih0, Wih0_bf, 1572864 },
    { Whh0, Whh0_bf, 786432 },
    { Wih1, Wih1_bf, 786432 },
    { Whh1, Whh1_bf, 786432 },
    { Wout, Wout_bf, 8192000 },
  };
  for (int i = 0; i < 8; ++i){
    int blocks = (cvs[i].n4 + 255) >> 8;
    if (blocks > 2048) blocks = 2048;
    k_f2bf<<<dim3(blocks), dim3(256), 0, stream>>>(cvs[i].s, cvs[i].d, cvs[i].n4);
  }
  k_init<<<dim3(NB), dim3(256), 0, stream>>>(h0, h0f, h1f, h0h, h1h);

  // kproj = encY @ Wk^T + bk -> bf16 [8192][1024]
  k_mfma_gemm<1><<<dim3(8, 64), dim3(256), 0, stream>>>(
      encY_bf, Wk_bf, bk, kproj_bf, 8192, 1024, 1024);

  for (int t = 0; t < NT; ++t){
    int cur = t & 1, nxt = cur ^ 1;
    float* h0fc = h0f + (size_t)cur*65536;
    float* h1fc = h1f + (size_t)cur*65536;
    float* h0fn = h0f + (size_t)nxt*65536;
    float* h1fn = h1f + (size_t)nxt*65536;
    unsigned short* h0hc = h0h + (size_t)cur*65536;
    unsigned short* h1hc = h1h + (size_t)cur*65536;
    unsigned short* h0hn = h0h + (size_t)nxt*65536;
    unsigned short* h1hn = h1h + (size_t)nxt*65536;

    // q partials: h1 @ Wq^T, K=1024 in 4 chunks of 256
    k_mfma_part<<<dim3(16, 4), dim3(256), 0, stream>>>(
        h1hc, Wq_bf, 1024, 1024, 4, h1hc, Wq_bf, 1024, 1024, 256, 1024, qpart);
    k_attn<<<dim3(NB), dim3(256), 0, stream>>>(
        qpart, bq, kproj_bf, encY_bf, wv, bv, X, table, t, A0bf);
    // GRU0: phase1 A0@Wih0 (K=2048, 4x512), phase2 h0@Whh0 (K=1024, 2x512)
    k_mfma_part<<<dim3(48, 6), dim3(256), 0, stream>>>(
        A0bf, Wih0_bf, 2048, 2048, 4, h0hc, Whh0_bf, 1024, 1024, 512, 3072, g0p);
    k_gru_cell<<<dim3(NB), dim3(256), 0, stream>>>(
        g0p, 4, 2, bih0, bhh0, h0fc, h0fn, h0hn, (unsigned short*)nullptr, 0);
    // GRU1: phase1 h0new@Wih1 (2x512), phase2 h1@Whh1 (2x512)
    k_mfma_part<<<dim3(48, 4), dim3(256), 0, stream>>>(
        h0hn, Wih1_bf, 1024, 1024, 2, h1hc, Whh1_bf, 1024, 1024, 512, 3072, g1p);
    k_gru_cell<<<dim3(NB), dim3(256), 0, stream>>>(
        g1p, 2, 2, bih1, bhh1, h1fc, h1fn, h1hn, ys_bf, t);
  }

  // logits = ys @ Wout^T + bout -> d_out fp32, then in-place log-softmax
  k_mfma_gemm<0><<<dim3(250, 32), dim3(256), 0, stream>>>(
      ys_bf, Wout_bf, bout, out, 4096, NV, 1024);
  k_logsoftmax<<<dim3(4096), dim3(1024), 0, stream>>>(out);
}